// Round 7
// baseline (87.701 us; speedup 1.0000x reference)
//
#include <hip/hip_runtime.h>
#include <hip/hip_bf16.h>

#define N_CLS 4096
#define FDIM  2048
#define ITERS 16          // 32 K-tiles of BK=64, 2 per iteration

typedef float  floatx4 __attribute__((ext_vector_type(4)));
typedef short  shortx8 __attribute__((ext_vector_type(8)));

__device__ __forceinline__ unsigned short f2bf(float x) {
    union { float f; unsigned int u; } v; v.f = x;
    unsigned int r = v.u + 0x7fffu + ((v.u >> 16) & 1u);
    return (unsigned short)(r >> 16);
}

__global__ void zero_kernel(float* __restrict__ accum) { *accum = 0.0f; }

// ---------------------------------------------------------------------------
// Kernel A: row norms, fp32 diag, bf16 conversion (HBM-roofline already).
// ---------------------------------------------------------------------------
__global__ __launch_bounds__(256) void prep_kernel(
    const float* __restrict__ bnd,
    const float* __restrict__ proto,
    const float* __restrict__ wgt,
    unsigned short* __restrict__ pbf,
    unsigned short* __restrict__ wbf,
    float* __restrict__ t1,
    float* __restrict__ cc)
{
    const int row = blockIdx.x;
    const int tid = threadIdx.x;
    const size_t base = (size_t)row * FDIM + (size_t)tid * 8;

    floatx4 p0 = *(const floatx4*)(proto + base);
    floatx4 p1 = *(const floatx4*)(proto + base + 4);
    floatx4 w0 = *(const floatx4*)(wgt + base);
    floatx4 w1 = *(const floatx4*)(wgt + base + 4);

    float ss = 0.f, dt = 0.f;
#pragma unroll
    for (int k = 0; k < 4; ++k) {
        ss += p0[k] * p0[k] + p1[k] * p1[k];
        dt += p0[k] * w0[k] + p1[k] * w1[k];
    }
#pragma unroll
    for (int off = 32; off > 0; off >>= 1) {
        ss += __shfl_down(ss, off);
        dt += __shfl_down(dt, off);
    }

    __shared__ float sss[4], sdt[4];
    __shared__ float srn;
    const int wid = tid >> 6, lane = tid & 63;
    if (lane == 0) { sss[wid] = ss; sdt[wid] = dt; }
    __syncthreads();
    if (tid == 0) {
        float SS = sss[0] + sss[1] + sss[2] + sss[3];
        float DT = sdt[0] + sdt[1] + sdt[2] + sdt[3];
        float rn = 1.0f / fmaxf(sqrtf(SS), 1e-12f);
        srn = rn;
        float bv = bnd[row];
        t1[row] = (1.0f - bv) * (DT * rn);
        cc[row] = bv - 1.0f;
    }
    __syncthreads();
    const float rn = srn;

    shortx8 pv, wv;
#pragma unroll
    for (int k = 0; k < 4; ++k) {
        pv[k]     = (short)f2bf(p0[k] * rn);
        pv[k + 4] = (short)f2bf(p1[k] * rn);
        wv[k]     = (short)f2bf(w0[k]);
        wv[k + 4] = (short)f2bf(w1[k]);
    }
    *(shortx8*)(pbf + base) = pv;
    *(shortx8*)(wbf + base) = wv;
}

// ---------------------------------------------------------------------------
// Kernel B: 8-phase GEMM, balanced reads (8/4/8/4), one stage per phase,
// counted vmcnt {8,10,8,4,8,10,8,4}. BM=BN=256, BK=64, 8 waves (2Mx4N),
// per-wave 128x64, acc[8][4]. fb01 (ni 0,1) read one tile ahead at P3/P7
// (after that phase's MFMA; WAR keeps ordering, single register set).
// Swizzle both-sides: elem col ^= (row&7)<<3 (verified conflict-free R4/R6).
// ---------------------------------------------------------------------------
#define PH_BAR() { __builtin_amdgcn_s_barrier(); __builtin_amdgcn_sched_barrier(0); }

#define RD_FA(D, MH)                                                           \
    _Pragma("unroll") for (int mi = 0; mi < 4; ++mi) {                         \
        fa[mi][0] = *(const shortx8*)&sAB[D][aoff + (MH)*4096 + mi*1024 + cx0];\
        fa[mi][1] = *(const shortx8*)&sAB[D][aoff + (MH)*4096 + mi*1024 + cx1];\
    }
#define RD_FB2(D, NI0)                                                         \
    _Pragma("unroll") for (int ni = 0; ni < 2; ++ni) {                         \
        fb[(NI0)+ni][0] = *(const shortx8*)&sAB[D][boff + ((NI0)+ni)*1024 + cx0];\
        fb[(NI0)+ni][1] = *(const shortx8*)&sAB[D][boff + ((NI0)+ni)*1024 + cx1];\
    }
#define MFMA_Q(MI0, NI0)                                                       \
    __builtin_amdgcn_s_setprio(1);                                             \
    _Pragma("unroll") for (int kx = 0; kx < 2; ++kx)                           \
    _Pragma("unroll") for (int mi = 0; mi < 4; ++mi)                           \
    _Pragma("unroll") for (int ni = 0; ni < 2; ++ni)                           \
        acc[(MI0)+mi][(NI0)+ni] = __builtin_amdgcn_mfma_f32_16x16x32_bf16(     \
            fa[mi][kx], fb[(NI0)+ni][kx], acc[(MI0)+mi][(NI0)+ni], 0, 0, 0);   \
    __builtin_amdgcn_s_setprio(0);

__global__ __launch_bounds__(512, 2) void gemm_reduce_kernel(
    const unsigned short* __restrict__ A,   // p_bf16 [4096][2048]
    const unsigned short* __restrict__ B,   // w_bf16 [4096][2048]
    const float* __restrict__ t1,
    const float* __restrict__ cc,
    float* __restrict__ accum)
{
    __shared__ unsigned short sAB[2][32768];  // per buf: A0|A1|B0|B1, 8192 each
    __shared__ float red[8];

    const int tid  = threadIdx.x;
    const int wid  = tid >> 6;
    const int lane = tid & 63;

    // XCD-aware bijective swizzle: 256 blocks over 16x16 tile grid.
    const int b   = blockIdx.x;
    const int xcd = b & 7, sl = b >> 3;
    const int bi  = ((xcd & 3) << 2) + (sl & 3);
    const int bj  = ((xcd >> 2) << 3) + (sl >> 2);
    const int arow0 = bi * 256;
    const int brow0 = bj * 256;

    const int wm = wid >> 2;   // 0..1 : 128-row strip
    const int wn = wid & 3;    // 0..3 : 64-col strip
    const int lr = lane & 15;

    // swizzled frag-read col offsets (shorts) for kx=0/1:
    const int cx0 = (((lane >> 4)    ) ^ (lane & 7)) << 3;
    const int cx1 = ((4 | (lane >> 4)) ^ (lane & 7)) << 3;
    // frag base offsets (shorts) within a buffer:
    const int aoff = wm * 8192 + lr * 64;
    const int boff = 16384 + (wn >> 1) * 8192 + (wn & 1) * 4096 + lr * 64;

    // staging: thread t covers rows {t>>3, 64+(t>>3)} of a half, 8 elems each;
    // global col pre-swizzled so LDS[r][c] = G[r][c ^ ((r&7)<<3)].
    const int srow = tid >> 3;
    const int sgc  = (((tid & 7) ^ ((tid >> 3) & 7)) << 3);

    auto glds = [&](const unsigned short* src, unsigned short* dst) {
        __builtin_amdgcn_global_load_lds(
            (const __attribute__((address_space(1))) void*)src,
            (__attribute__((address_space(3))) void*)dst, 16, 0, 0);
    };
    auto stageA = [&](int h, int t) {
        unsigned short* dst = &sAB[t & 1][h * 8192 + tid * 8];
        const unsigned short* src =
            A + (size_t)(arow0 + h * 128 + srow) * FDIM + t * 64 + sgc;
        glds(src, dst);
        glds(src + (size_t)64 * FDIM, dst + 4096);
    };
    auto stageB = [&](int h, int t) {
        unsigned short* dst = &sAB[t & 1][16384 + h * 8192 + tid * 8];
        const unsigned short* src =
            B + (size_t)(brow0 + h * 128 + srow) * FDIM + t * 64 + sgc;
        glds(src, dst);
        glds(src + (size_t)64 * FDIM, dst + 4096);
    };

    floatx4 acc[8][4];
#pragma unroll
    for (int m = 0; m < 8; ++m)
#pragma unroll
        for (int n = 0; n < 4; ++n) acc[m][n] = (floatx4)0.0f;

    shortx8 fa[4][2];   // current A-half frags [mi][kx]
    shortx8 fb[4][2];   // B frags for current tile [ni][kx]

    // ---- prologue: buf0 tile0 {B0,A0,B1,A1} + buf1 tile1 {B0,A0,B1}
    // (A1(1) is staged at P0 of iter 0). 7 calls = 14 loads.
    stageB(0, 0); stageA(0, 0); stageB(1, 0); stageA(1, 0);
    stageB(0, 1); stageA(0, 1); stageB(1, 1);
    asm volatile("s_waitcnt vmcnt(8)" ::: "memory");   // B0(0),B1(0) landed
    PH_BAR();
    RD_FB2(0, 0);   // fb01(tile 0)

#pragma unroll 1
    for (int i = 0; i < ITERS; ++i) {
        // tail clamp (parity-preserving): re-stages byte-identical data
        const int t2 = (2 * i + 2 > 31) ? 2 * i     : 2 * i + 2;
        const int t3 = (2 * i + 3 > 31) ? 2 * i + 1 : 2 * i + 3;

        // P0: rd A0(u) | stage A1(u+1)->buf1 | MFMA (0,0)u
        asm volatile("s_waitcnt vmcnt(8)" ::: "memory");
        PH_BAR();
        RD_FA(0, 0);
        stageA(1, 2 * i + 1);
        MFMA_Q(0, 0);
        // P1: rd B(nh1)(u) | MFMA (0,2)u
        asm volatile("s_waitcnt vmcnt(10)" ::: "memory");
        PH_BAR();
        RD_FB2(0, 2);
        MFMA_Q(0, 2);
        // P2: rd A1(u) | stage B0(u+2) | MFMA (4,2)u
        asm volatile("s_waitcnt vmcnt(8)" ::: "memory");
        PH_BAR();
        RD_FA(0, 1);
        stageB(0, t2);
        MFMA_Q(4, 2);
        // P3: MFMA (4,0)u | stage A0(u+2),B1(u+2) | rd fb01(v) (one ahead)
        asm volatile("s_waitcnt vmcnt(4)" ::: "memory");
        PH_BAR();
        MFMA_Q(4, 0);
        stageA(0, t2); stageB(1, t2);
        RD_FB2(1, 0);
        // P4: rd A0(v) | stage A1(u+2) | MFMA (0,0)v
        asm volatile("s_waitcnt vmcnt(8)" ::: "memory");
        PH_BAR();
        RD_FA(1, 0);
        stageA(1, t2);
        MFMA_Q(0, 0);
        // P5: rd B(nh1)(v) | MFMA (0,2)v
        asm volatile("s_waitcnt vmcnt(10)" ::: "memory");
        PH_BAR();
        RD_FB2(1, 2);
        MFMA_Q(0, 2);
        // P6: rd A1(v) | stage B0(v+2) | MFMA (4,2)v
        asm volatile("s_waitcnt vmcnt(8)" ::: "memory");
        PH_BAR();
        RD_FA(1, 1);
        stageB(0, t3);
        MFMA_Q(4, 2);
        // P7: MFMA (4,0)v | stage A0(v+2),B1(v+2) | rd fb01(u+2) (one ahead)
        asm volatile("s_waitcnt vmcnt(4)" ::: "memory");
        PH_BAR();
        MFMA_Q(4, 0);
        stageA(0, t3); stageB(1, t3);
        RD_FB2(0, 0);
    }

    // ---- epilogue: val = relu(t1[i] + s_ij*c[j]), skip i==j, global sum.
    // C/D layout: col = lane&15, row = (lane>>4)*4 + reg  [m89-verified]
    const int row0 = arow0 + wm * 128 + (lane >> 4) * 4;
    const int col0 = brow0 + wn * 64 + lr;

    float local = 0.f;
#pragma unroll
    for (int n = 0; n < 4; ++n) {
        const int j = col0 + n * 16;
        const float cj = cc[j];
#pragma unroll
        for (int m = 0; m < 8; ++m) {
#pragma unroll
            for (int r = 0; r < 4; ++r) {
                const int i = row0 + m * 16 + r;
                float v = fmaxf(t1[i] + acc[m][n][r] * cj, 0.f);
                local += (i == j) ? 0.f : v;
            }
        }
    }

#pragma unroll
    for (int off = 32; off > 0; off >>= 1)
        local += __shfl_down(local, off);
    if (lane == 0) red[wid] = local;
    __syncthreads();
    if (tid == 0) {
        float s = 0.f;
#pragma unroll
        for (int w = 0; w < 8; ++w) s += red[w];
        atomicAdd(accum, s);
    }
}

__global__ void finalize_kernel(const float* __restrict__ accum,
                                float* __restrict__ out)
{
    const float denom = 4096.0f * 4095.0f;  // exact in fp32
    out[0] = *accum / denom;
}

extern "C" void kernel_launch(void* const* d_in, const int* in_sizes, int n_in,
                              void* d_out, int out_size, void* d_ws, size_t ws_size,
                              hipStream_t stream) {
    const float* bnd   = (const float*)d_in[0];
    const float* proto = (const float*)d_in[1];
    const float* wgt   = (const float*)d_in[2];

    char* ws = (char*)d_ws;
    unsigned short* pbf = (unsigned short*)ws;                              // 16 MB
    unsigned short* wbf = (unsigned short*)(ws + (size_t)N_CLS * FDIM * 2); // 16 MB
    float* t1    = (float*)(ws + (size_t)N_CLS * FDIM * 4);
    float* cc    = t1 + N_CLS;
    float* accum = cc + N_CLS;

    zero_kernel<<<1, 1, 0, stream>>>(accum);
    prep_kernel<<<N_CLS, 256, 0, stream>>>(bnd, proto, wgt, pbf, wbf, t1, cc);
    gemm_reduce_kernel<<<256, 512, 0, stream>>>(pbf, wbf, t1, cc, accum);
    finalize_kernel<<<1, 1, 0, stream>>>(accum, (float*)d_out);
}

// Round 8
// 82.580 us; speedup vs baseline: 1.0620x; 1.0620x over previous
//
#include <hip/hip_runtime.h>
#include <hip/hip_bf16.h>

#define N_CLS 4096
#define FDIM  2048
#define ITERS 16          // 32 K-tiles of BK=64, 2 per iteration

typedef float  floatx4 __attribute__((ext_vector_type(4)));
typedef short  shortx8 __attribute__((ext_vector_type(8)));

__device__ __forceinline__ unsigned short f2bf(float x) {
    union { float f; unsigned int u; } v; v.f = x;
    unsigned int r = v.u + 0x7fffu + ((v.u >> 16) & 1u);
    return (unsigned short)(r >> 16);
}

__global__ void zero_kernel(float* __restrict__ accum) { *accum = 0.0f; }

// ---------------------------------------------------------------------------
// Kernel A: row norms, fp32 diag, bf16 conversion (HBM-roofline already).
// ---------------------------------------------------------------------------
__global__ __launch_bounds__(256) void prep_kernel(
    const float* __restrict__ bnd,
    const float* __restrict__ proto,
    const float* __restrict__ wgt,
    unsigned short* __restrict__ pbf,
    unsigned short* __restrict__ wbf,
    float* __restrict__ t1,
    float* __restrict__ cc)
{
    const int row = blockIdx.x;
    const int tid = threadIdx.x;
    const size_t base = (size_t)row * FDIM + (size_t)tid * 8;

    floatx4 p0 = *(const floatx4*)(proto + base);
    floatx4 p1 = *(const floatx4*)(proto + base + 4);
    floatx4 w0 = *(const floatx4*)(wgt + base);
    floatx4 w1 = *(const floatx4*)(wgt + base + 4);

    float ss = 0.f, dt = 0.f;
#pragma unroll
    for (int k = 0; k < 4; ++k) {
        ss += p0[k] * p0[k] + p1[k] * p1[k];
        dt += p0[k] * w0[k] + p1[k] * w1[k];
    }
#pragma unroll
    for (int off = 32; off > 0; off >>= 1) {
        ss += __shfl_down(ss, off);
        dt += __shfl_down(dt, off);
    }

    __shared__ float sss[4], sdt[4];
    __shared__ float srn;
    const int wid = tid >> 6, lane = tid & 63;
    if (lane == 0) { sss[wid] = ss; sdt[wid] = dt; }
    __syncthreads();
    if (tid == 0) {
        float SS = sss[0] + sss[1] + sss[2] + sss[3];
        float DT = sdt[0] + sdt[1] + sdt[2] + sdt[3];
        float rn = 1.0f / fmaxf(sqrtf(SS), 1e-12f);
        srn = rn;
        float bv = bnd[row];
        t1[row] = (1.0f - bv) * (DT * rn);
        cc[row] = bv - 1.0f;
    }
    __syncthreads();
    const float rn = srn;

    shortx8 pv, wv;
#pragma unroll
    for (int k = 0; k < 4; ++k) {
        pv[k]     = (short)f2bf(p0[k] * rn);
        pv[k + 4] = (short)f2bf(p1[k] * rn);
        wv[k]     = (short)f2bf(w0[k]);
        wv[k + 4] = (short)f2bf(w1[k]);
    }
    *(shortx8*)(pbf + base) = pv;
    *(shortx8*)(wbf + base) = wv;
}

// ---------------------------------------------------------------------------
// Kernel B: 8-phase GEMM with ds_reads pipelined ONE PHASE AHEAD of their
// MFMA (m201 mechanism): body = {MFMA_p; vmcnt(N); s_barrier; reads_{p+1};
// stage; sched_barrier}. vmcnt ledger {10,10,-,8,10,10,-,8} (never <8).
// BM=BN=256, BK=64, 8 waves (2Mx4N), per-wave 128x64, acc[8][4].
// Stage plan (1 region/phase): P0:A0(u+2) P1:B0(u+2) P2:B1(u+2) P3:A1(u+2)
// P4:A0(v+2) P5:B0(v+2) P6:B1(v+2) P7:A1(v+2); every stage lands >=1 barrier
// after its region's last reader's operand-wait (proof per region).
// Swizzle both-sides: elem col ^= (row&7)<<3 (verified conflict-free R4/R6).
// ---------------------------------------------------------------------------
#define SB0() __builtin_amdgcn_sched_barrier(0)

#define RD_FA(D, MH)                                                           \
    _Pragma("unroll") for (int mi = 0; mi < 4; ++mi) {                         \
        fa[mi][0] = *(const shortx8*)&sAB[D][aoff + (MH)*4096 + mi*1024 + cx0];\
        fa[mi][1] = *(const shortx8*)&sAB[D][aoff + (MH)*4096 + mi*1024 + cx1];\
    }
#define RD_FB2(D, NI0)                                                         \
    _Pragma("unroll") for (int ni = 0; ni < 2; ++ni) {                         \
        fb[(NI0)+ni][0] = *(const shortx8*)&sAB[D][boff + ((NI0)+ni)*1024 + cx0];\
        fb[(NI0)+ni][1] = *(const shortx8*)&sAB[D][boff + ((NI0)+ni)*1024 + cx1];\
    }
#define MFMA_Q(MI0, NI0)                                                       \
    __builtin_amdgcn_s_setprio(1);                                             \
    _Pragma("unroll") for (int kx = 0; kx < 2; ++kx)                           \
    _Pragma("unroll") for (int mi = 0; mi < 4; ++mi)                           \
    _Pragma("unroll") for (int ni = 0; ni < 2; ++ni)                           \
        acc[(MI0)+mi][(NI0)+ni] = __builtin_amdgcn_mfma_f32_16x16x32_bf16(     \
            fa[mi][kx], fb[(NI0)+ni][kx], acc[(MI0)+mi][(NI0)+ni], 0, 0, 0);   \
    __builtin_amdgcn_s_setprio(0);

#define VMCNT(N) asm volatile("s_waitcnt vmcnt(" #N ")" ::: "memory")

__global__ __launch_bounds__(512, 2) void gemm_reduce_kernel(
    const unsigned short* __restrict__ A,   // p_bf16 [4096][2048]
    const unsigned short* __restrict__ B,   // w_bf16 [4096][2048]
    const float* __restrict__ t1,
    const float* __restrict__ cc,
    float* __restrict__ accum)
{
    __shared__ unsigned short sAB[2][32768];  // per buf: A0|A1|B0|B1, 8192 each
    __shared__ float red[8];

    const int tid  = threadIdx.x;
    const int wid  = tid >> 6;
    const int lane = tid & 63;

    // XCD-aware bijective swizzle: 256 blocks over 16x16 tile grid.
    const int b   = blockIdx.x;
    const int xcd = b & 7, sl = b >> 3;
    const int bi  = ((xcd & 3) << 2) + (sl & 3);
    const int bj  = ((xcd >> 2) << 3) + (sl >> 2);
    const int arow0 = bi * 256;
    const int brow0 = bj * 256;

    const int wm = wid >> 2;   // 0..1 : 128-row strip
    const int wn = wid & 3;    // 0..3 : 64-col strip
    const int lr = lane & 15;

    // swizzled frag-read col offsets (shorts) for kx=0/1:
    const int cx0 = (((lane >> 4)    ) ^ (lane & 7)) << 3;
    const int cx1 = ((4 | (lane >> 4)) ^ (lane & 7)) << 3;
    // frag base offsets (shorts) within a buffer:
    const int aoff = wm * 8192 + lr * 64;
    const int boff = 16384 + (wn >> 1) * 8192 + (wn & 1) * 4096 + lr * 64;

    // staging: thread t covers rows {t>>3, 64+(t>>3)} of a half, 8 elems each;
    // global col pre-swizzled so LDS[r][c] = G[r][c ^ ((r&7)<<3)].
    const int srow = tid >> 3;
    const int sgc  = (((tid & 7) ^ ((tid >> 3) & 7)) << 3);

    auto glds = [&](const unsigned short* src, unsigned short* dst) {
        __builtin_amdgcn_global_load_lds(
            (const __attribute__((address_space(1))) void*)src,
            (__attribute__((address_space(3))) void*)dst, 16, 0, 0);
    };
    auto stageA = [&](int h, int t) {
        unsigned short* dst = &sAB[t & 1][h * 8192 + tid * 8];
        const unsigned short* src =
            A + (size_t)(arow0 + h * 128 + srow) * FDIM + t * 64 + sgc;
        glds(src, dst);
        glds(src + (size_t)64 * FDIM, dst + 4096);
    };
    auto stageB = [&](int h, int t) {
        unsigned short* dst = &sAB[t & 1][16384 + h * 8192 + tid * 8];
        const unsigned short* src =
            B + (size_t)(brow0 + h * 128 + srow) * FDIM + t * 64 + sgc;
        glds(src, dst);
        glds(src + (size_t)64 * FDIM, dst + 4096);
    };

    floatx4 acc[8][4];
#pragma unroll
    for (int m = 0; m < 8; ++m)
#pragma unroll
        for (int n = 0; n < 4; ++n) acc[m][n] = (floatx4)0.0f;

    shortx8 fa[4][2];   // current A-half frags [mi][kx]
    shortx8 fb[4][2];   // B frags for current tile [ni][kx]

    // ---- prologue: tiles 0,1 in steady-state region order {A0,B0,B1,A1}
    stageA(0, 0); stageB(0, 0); stageB(1, 0); stageA(1, 0);
    stageA(0, 1); stageB(0, 1); stageB(1, 1); stageA(1, 1);
    // pre-body (iter -1, P7-equivalent): A0(0),B0(0),B1(0) landed; 5 calls
    // (A1(0)..A1(1)) = 10 loads may stay in flight.
    VMCNT(10);
    __builtin_amdgcn_s_barrier();
    SB0();
    RD_FA(0, 0);    // fa = A0(0)
    RD_FB2(0, 0);   // fb01(0)
    SB0();

#pragma unroll 1
    for (int i = 0; i < ITERS; ++i) {
        // tail clamp (parity-preserving): re-stages byte-identical data
        const int t2 = (2 * i + 2 > 31) ? 2 * i     : 2 * i + 2;  // buf0
        const int t3 = (2 * i + 3 > 31) ? 2 * i + 1 : 2 * i + 3;  // buf1

        // P0: MFMA (0,0)u | rd fb23(u) | stage A0(u+2)
        MFMA_Q(0, 0);
        VMCNT(10);
        __builtin_amdgcn_s_barrier();
        SB0();
        RD_FB2(0, 2);
        stageA(0, t2);
        SB0();
        // P1: MFMA (0,2)u | rd A1(u) | stage B0(u+2)
        MFMA_Q(0, 2);
        VMCNT(10);
        __builtin_amdgcn_s_barrier();
        SB0();
        RD_FA(0, 1);
        stageB(0, t2);
        SB0();
        // P2: MFMA (4,2)u | stage B1(u+2)
        MFMA_Q(4, 2);
        __builtin_amdgcn_s_barrier();
        SB0();
        stageB(1, t2);
        SB0();
        // P3: MFMA (4,0)u | rd A0(v), fb01(v) | stage A1(u+2)
        MFMA_Q(4, 0);
        VMCNT(8);
        __builtin_amdgcn_s_barrier();
        SB0();
        RD_FA(1, 0);
        RD_FB2(1, 0);
        stageA(1, t2);
        SB0();
        // P4: MFMA (0,0)v | rd fb23(v) | stage A0(v+2)
        MFMA_Q(0, 0);
        VMCNT(10);
        __builtin_amdgcn_s_barrier();
        SB0();
        RD_FB2(1, 2);
        stageA(0, t3);
        SB0();
        // P5: MFMA (0,2)v | rd A1(v) | stage B0(v+2)
        MFMA_Q(0, 2);
        VMCNT(10);
        __builtin_amdgcn_s_barrier();
        SB0();
        RD_FA(1, 1);
        stageB(0, t3);
        SB0();
        // P6: MFMA (4,2)v | stage B1(v+2)
        MFMA_Q(4, 2);
        __builtin_amdgcn_s_barrier();
        SB0();
        stageB(1, t3);
        SB0();
        // P7: MFMA (4,0)v | rd A0(u+2), fb01(u+2) | stage A1(v+2)
        MFMA_Q(4, 0);
        VMCNT(8);
        __builtin_amdgcn_s_barrier();
        SB0();
        RD_FA(0, 0);
        RD_FB2(0, 0);
        stageA(1, t3);
        SB0();
    }

    // ---- epilogue: val = relu(t1[i] + s_ij*c[j]), skip i==j, global sum.
    // C/D layout: col = lane&15, row = (lane>>4)*4 + reg  [m89-verified]
    const int row0 = arow0 + wm * 128 + (lane >> 4) * 4;
    const int col0 = brow0 + wn * 64 + lr;

    float local = 0.f;
#pragma unroll
    for (int n = 0; n < 4; ++n) {
        const int j = col0 + n * 16;
        const float cj = cc[j];
#pragma unroll
        for (int m = 0; m < 8; ++m) {
#pragma unroll
            for (int r = 0; r < 4; ++r) {
                const int i = row0 + m * 16 + r;
                float v = fmaxf(t1[i] + acc[m][n][r] * cj, 0.f);
                local += (i == j) ? 0.f : v;
            }
        }
    }

#pragma unroll
    for (int off = 32; off > 0; off >>= 1)
        local += __shfl_down(local, off);
    if (lane == 0) red[wid] = local;
    __syncthreads();
    if (tid == 0) {
        float s = 0.f;
#pragma unroll
        for (int w = 0; w < 8; ++w) s += red[w];
        atomicAdd(accum, s);
    }
}

__global__ void finalize_kernel(const float* __restrict__ accum,
                                float* __restrict__ out)
{
    const float denom = 4096.0f * 4095.0f;  // exact in fp32
    out[0] = *accum / denom;
}

extern "C" void kernel_launch(void* const* d_in, const int* in_sizes, int n_in,
                              void* d_out, int out_size, void* d_ws, size_t ws_size,
                              hipStream_t stream) {
    const float* bnd   = (const float*)d_in[0];
    const float* proto = (const float*)d_in[1];
    const float* wgt   = (const float*)d_in[2];

    char* ws = (char*)d_ws;
    unsigned short* pbf = (unsigned short*)ws;                              // 16 MB
    unsigned short* wbf = (unsigned short*)(ws + (size_t)N_CLS * FDIM * 2); // 16 MB
    float* t1    = (float*)(ws + (size_t)N_CLS * FDIM * 4);
    float* cc    = t1 + N_CLS;
    float* accum = cc + N_CLS;

    zero_kernel<<<1, 1, 0, stream>>>(accum);
    prep_kernel<<<N_CLS, 256, 0, stream>>>(bnd, proto, wgt, pbf, wbf, t1, cc);
    gemm_reduce_kernel<<<256, 512, 0, stream>>>(pbf, wbf, t1, cc, accum);
    finalize_kernel<<<1, 1, 0, stream>>>(accum, (float*)d_out);
}

// Round 9
// 63.835 us; speedup vs baseline: 1.3739x; 1.2937x over previous
//
#include <hip/hip_runtime.h>
#include <hip/hip_bf16.h>

#define N_CLS 4096
#define FDIM  2048
#define ITERS 8           // 16 K-tiles of BK=128 (fp8), 2 per iteration

typedef float  floatx4 __attribute__((ext_vector_type(4)));
typedef int    intx2   __attribute__((ext_vector_type(2)));
typedef int    intx4   __attribute__((ext_vector_type(4)));
typedef int    intx8   __attribute__((ext_vector_type(8)));

__global__ void zero_kernel(float* __restrict__ accum) { *accum = 0.0f; }

// ---------------------------------------------------------------------------
// Kernel A: row norms, fp32 diag, fp8-e4m3 conversion (hw cvt_pk, RNE).
// ---------------------------------------------------------------------------
__global__ __launch_bounds__(256) void prep_kernel(
    const float* __restrict__ bnd,
    const float* __restrict__ proto,
    const float* __restrict__ wgt,
    unsigned char* __restrict__ pf8,
    unsigned char* __restrict__ wf8,
    float* __restrict__ t1,
    float* __restrict__ cc)
{
    const int row = blockIdx.x;
    const int tid = threadIdx.x;
    const size_t base = (size_t)row * FDIM + (size_t)tid * 8;

    floatx4 p0 = *(const floatx4*)(proto + base);
    floatx4 p1 = *(const floatx4*)(proto + base + 4);
    floatx4 w0 = *(const floatx4*)(wgt + base);
    floatx4 w1 = *(const floatx4*)(wgt + base + 4);

    float ss = 0.f, dt = 0.f;
#pragma unroll
    for (int k = 0; k < 4; ++k) {
        ss += p0[k] * p0[k] + p1[k] * p1[k];
        dt += p0[k] * w0[k] + p1[k] * w1[k];
    }
#pragma unroll
    for (int off = 32; off > 0; off >>= 1) {
        ss += __shfl_down(ss, off);
        dt += __shfl_down(dt, off);
    }

    __shared__ float sss[4], sdt[4];
    __shared__ float srn;
    const int wid = tid >> 6, lane = tid & 63;
    if (lane == 0) { sss[wid] = ss; sdt[wid] = dt; }
    __syncthreads();
    if (tid == 0) {
        float SS = sss[0] + sss[1] + sss[2] + sss[3];
        float DT = sdt[0] + sdt[1] + sdt[2] + sdt[3];
        float rn = 1.0f / fmaxf(sqrtf(SS), 1e-12f);
        srn = rn;
        float bv = bnd[row];
        t1[row] = (1.0f - bv) * (DT * rn);   // (1-b_i)*diag_i, fp32 exact
        cc[row] = bv - 1.0f;
    }
    __syncthreads();
    const float rn = srn;

    intx2 pv, wv;
    {
        int a = __builtin_amdgcn_cvt_pk_fp8_f32(p0[0] * rn, p0[1] * rn, 0, 0);
        a     = __builtin_amdgcn_cvt_pk_fp8_f32(p0[2] * rn, p0[3] * rn, a, 1);
        int b = __builtin_amdgcn_cvt_pk_fp8_f32(p1[0] * rn, p1[1] * rn, 0, 0);
        b     = __builtin_amdgcn_cvt_pk_fp8_f32(p1[2] * rn, p1[3] * rn, b, 1);
        pv[0] = a; pv[1] = b;
        int c = __builtin_amdgcn_cvt_pk_fp8_f32(w0[0], w0[1], 0, 0);
        c     = __builtin_amdgcn_cvt_pk_fp8_f32(w0[2], w0[3], c, 1);
        int d = __builtin_amdgcn_cvt_pk_fp8_f32(w1[0], w1[1], 0, 0);
        d     = __builtin_amdgcn_cvt_pk_fp8_f32(w1[2], w1[3], d, 1);
        wv[0] = c; wv[1] = d;
    }
    *(intx2*)(pf8 + base) = pv;
    *(intx2*)(wf8 + base) = wv;
}

// ---------------------------------------------------------------------------
// Kernel B: MX-fp8 8-phase GEMM (scales = 1.0) + fused relu-sum epilogue.
// R6-proven skeleton: BM=BN=256, BK=128(fp8) [byte-identical regions to
// bf16 BK=64], 8 waves (2Mx4N), per-wave 128x64, acc[8][4], 2x64KB LDS dbuf,
// stage slots + vmcnt ledger {8,12,10,-} + tail peel copied verbatim.
// MFMA: mfma_scale_f32_16x16x128_f8f6f4, fmt=0 (e4m3), scale=0x7F7F7F7F (2^0).
// LDS rows = 128 B = 8 x 16B pairs; swizzle pair ^= (row&7), both sides
// (pre-swizzled global src for linear global_load_lds + swizzled ds_read):
// uniform 8 bank-accesses per b128 -> conflict-free.
// ---------------------------------------------------------------------------
#define PH_BAR() { __builtin_amdgcn_s_barrier(); __builtin_amdgcn_sched_barrier(0); }
#define VMCNT(N) asm volatile("s_waitcnt vmcnt(" #N ")" ::: "memory")

#define RD_FA(D, MH)                                                           \
    _Pragma("unroll") for (int mi = 0; mi < 4; ++mi) {                         \
        const unsigned char* bp = &sAB[D][aoff + ((MH)*64 + mi*16) * 128];     \
        intx4 lo = *(const intx4*)(bp + cq0);                                  \
        intx4 hi = *(const intx4*)(bp + cq1);                                  \
        fa[mi] = __builtin_shufflevector(lo, hi, 0, 1, 2, 3, 4, 5, 6, 7);      \
    }
#define RD_FB2(D, NI0)                                                         \
    _Pragma("unroll") for (int ni = 0; ni < 2; ++ni) {                         \
        const unsigned char* bp = &sAB[D][boff + ((NI0)+ni) * 2048];           \
        intx4 lo = *(const intx4*)(bp + cq0);                                  \
        intx4 hi = *(const intx4*)(bp + cq1);                                  \
        fb[(NI0)+ni] = __builtin_shufflevector(lo, hi, 0, 1, 2, 3, 4, 5, 6, 7);\
    }
#define MFMA_Q(MI0, NI0)                                                       \
    __builtin_amdgcn_s_setprio(1);                                             \
    _Pragma("unroll") for (int mi = 0; mi < 4; ++mi)                           \
    _Pragma("unroll") for (int ni = 0; ni < 2; ++ni)                           \
        acc[(MI0)+mi][(NI0)+ni] =                                              \
            __builtin_amdgcn_mfma_scale_f32_16x16x128_f8f6f4(                  \
                fa[mi], fb[(NI0)+ni], acc[(MI0)+mi][(NI0)+ni],                 \
                0, 0, 0, SC1, 0, SC1);                                         \
    __builtin_amdgcn_s_setprio(0);

__global__ __launch_bounds__(512, 2) void gemm_reduce_kernel(
    const unsigned char* __restrict__ A,   // p_fp8 [4096][2048]
    const unsigned char* __restrict__ B,   // w_fp8 [4096][2048]
    const float* __restrict__ t1,
    const float* __restrict__ cc,
    float* __restrict__ accum)
{
    __shared__ unsigned char sAB[2][65536];  // per buf: A0|A1|B0|B1, 16KB each
    __shared__ float red[8];

    const int tid  = threadIdx.x;
    const int wid  = tid >> 6;
    const int lane = tid & 63;
    const int SC1  = 0x7F7F7F7F;   // e8m0 = 127 -> 2^0 for all 4 K-blocks

    // XCD-aware bijective swizzle: 256 blocks over 16x16 tile grid.
    const int b   = blockIdx.x;
    const int xcd = b & 7, sl = b >> 3;
    const int bi  = ((xcd & 3) << 2) + (sl & 3);
    const int bj  = ((xcd >> 2) << 3) + (sl >> 2);
    const int arow0 = bi * 256;
    const int brow0 = bj * 256;

    const int wm = wid >> 2;   // 0..1 : 128-row strip (region A_wm)
    const int wn = wid & 3;    // 0..3 : 64-col strip
    const int lr = lane & 15;
    const int q  = lane >> 4;  // k-quarter: k = q*32 + 0..31
    const int r7 = lane & 7;

    // swizzled byte offsets of the two 16B halves of a 32B frag (pair ^= row&7)
    const int cq0 = ((2 * q)     ^ r7) << 4;
    const int cq1 = ((2 * q + 1) ^ r7) << 4;
    // frag base byte offsets within a buffer:
    const int aoff = wm * 16384 + lr * 128;
    const int boff = 32768 + (wn >> 1) * 16384 + (wn & 1) * 8192 + lr * 128;

    // staging: thread t covers rows {t>>3, 64+(t>>3)} of a 128x128B region,
    // 16 B each; global col pre-swizzled: LDS[r][pair p] = G[r][p ^ (r&7)].
    const int srow = tid >> 3;
    const int sgc  = ((tid & 7) ^ ((tid >> 3) & 7)) << 4;

    auto glds = [&](const unsigned char* src, unsigned char* dst) {
        __builtin_amdgcn_global_load_lds(
            (const __attribute__((address_space(1))) void*)src,
            (__attribute__((address_space(3))) void*)dst, 16, 0, 0);
    };
    auto stageA = [&](int h, int t) {
        unsigned char* dst = &sAB[t & 1][h * 16384 + tid * 16];
        const unsigned char* src =
            A + (size_t)(arow0 + h * 128 + srow) * FDIM + t * 128 + sgc;
        glds(src, dst);
        glds(src + (size_t)64 * FDIM, dst + 8192);
    };
    auto stageB = [&](int h, int t) {
        unsigned char* dst = &sAB[t & 1][32768 + h * 16384 + tid * 16];
        const unsigned char* src =
            B + (size_t)(brow0 + h * 128 + srow) * FDIM + t * 128 + sgc;
        glds(src, dst);
        glds(src + (size_t)64 * FDIM, dst + 8192);
    };

    floatx4 acc[8][4];
#pragma unroll
    for (int m = 0; m < 8; ++m)
#pragma unroll
        for (int n = 0; n < 4; ++n) acc[m][n] = (floatx4)0.0f;

    intx8 fa[4];   // current A-half frags [mi] (32 B each)
    intx8 fb[4];   // B frags for current tile [ni]

    // ---- prologue: tiles 0,1 (7 regions; A1(1) staged at P0 of iter 0)
    stageB(0, 0); stageB(1, 0); stageA(0, 0); stageA(1, 0);
    stageB(0, 1); stageB(1, 1); stageA(0, 1);
    VMCNT(6);     // all 4 regions of tile 0 landed (closes R6's latent race)
    PH_BAR();

#pragma unroll 1
    for (int i = 0; i < ITERS - 1; ++i) {
        const int c2 = 2 * i + 2, c3 = 2 * i + 3;
        // P0: rd A(mh0)(u), fb01(u) | stage A1(u+1) | MFMA (0,0)
        VMCNT(8);
        PH_BAR();
        RD_FA(0, 0); RD_FB2(0, 0);
        stageA(1, 2 * i + 1);
        MFMA_Q(0, 0);
        // P1: rd fb23(u) | stage B0(u+2) | MFMA (0,2)
        VMCNT(12);
        PH_BAR();
        RD_FB2(0, 2);
        stageB(0, c2);
        MFMA_Q(0, 2);
        // P2: rd A(mh1)(u) | stage B1(u+2) | MFMA (4,2)
        VMCNT(10);
        PH_BAR();
        RD_FA(0, 1);
        stageB(1, c2);
        MFMA_Q(4, 2);
        // P3: stage A0(u+2) | MFMA (4,0)
        PH_BAR();
        stageA(0, c2);
        MFMA_Q(4, 0);
        // P4: rd A(mh0)(v), fb01(v) | stage A1(u+2) | MFMA (0,0)
        VMCNT(8);
        PH_BAR();
        RD_FA(1, 0); RD_FB2(1, 0);
        stageA(1, c2);
        MFMA_Q(0, 0);
        // P5: rd fb23(v) | stage B0(v+2) | MFMA (0,2)
        VMCNT(12);
        PH_BAR();
        RD_FB2(1, 2);
        stageB(0, c3);
        MFMA_Q(0, 2);
        // P6: rd A(mh1)(v) | stage B1(v+2) | MFMA (4,2)
        VMCNT(10);
        PH_BAR();
        RD_FA(1, 1);
        stageB(1, c3);
        MFMA_Q(4, 2);
        // P7: stage A0(v+2) | MFMA (4,0)
        PH_BAR();
        stageA(0, c3);
        MFMA_Q(4, 0);
    }

    // ---- peeled tail (tiles 14, 15): only A1(15) still to stage
    {
        VMCNT(0);
        PH_BAR();
        RD_FA(0, 0); RD_FB2(0, 0);
        stageA(1, 15);
        MFMA_Q(0, 0);
        PH_BAR();
        RD_FB2(0, 2);
        MFMA_Q(0, 2);
        PH_BAR();
        RD_FA(0, 1);
        MFMA_Q(4, 2);
        PH_BAR();
        MFMA_Q(4, 0);
        PH_BAR();
        RD_FA(1, 0); RD_FB2(1, 0);
        MFMA_Q(0, 0);
        PH_BAR();
        RD_FB2(1, 2);
        MFMA_Q(0, 2);
        VMCNT(0);
        PH_BAR();
        RD_FA(1, 1);
        MFMA_Q(4, 2);
        PH_BAR();
        MFMA_Q(4, 0);
    }

    // ---- epilogue: val = relu(t1[i] + s_ij*c[j]), skip i==j, global sum.
    // C/D layout shape-determined (dtype-independent): col=lane&15,
    // row=(lane>>4)*4+reg.
    const int row0 = arow0 + wm * 128 + (lane >> 4) * 4;
    const int col0 = brow0 + wn * 64 + lr;

    float local = 0.f;
#pragma unroll
    for (int n = 0; n < 4; ++n) {
        const int j = col0 + n * 16;
        const float cj = cc[j];
#pragma unroll
        for (int m = 0; m < 8; ++m) {
#pragma unroll
            for (int r = 0; r < 4; ++r) {
                const int i = row0 + m * 16 + r;
                float v = fmaxf(t1[i] + acc[m][n][r] * cj, 0.f);
                local += (i == j) ? 0.f : v;
            }
        }
    }

#pragma unroll
    for (int off = 32; off > 0; off >>= 1)
        local += __shfl_down(local, off);
    if (lane == 0) red[wid] = local;
    __syncthreads();
    if (tid == 0) {
        float s = 0.f;
#pragma unroll
        for (int w = 0; w < 8; ++w) s += red[w];
        atomicAdd(accum, s);
    }
}

__global__ void finalize_kernel(const float* __restrict__ accum,
                                float* __restrict__ out)
{
    const float denom = 4096.0f * 4095.0f;  // exact in fp32
    out[0] = *accum / denom;
}

extern "C" void kernel_launch(void* const* d_in, const int* in_sizes, int n_in,
                              void* d_out, int out_size, void* d_ws, size_t ws_size,
                              hipStream_t stream) {
    const float* bnd   = (const float*)d_in[0];
    const float* proto = (const float*)d_in[1];
    const float* wgt   = (const float*)d_in[2];

    char* ws = (char*)d_ws;
    unsigned char* pf8 = (unsigned char*)ws;                               // 8 MB
    unsigned char* wf8 = (unsigned char*)(ws + (size_t)N_CLS * FDIM);      // 8 MB
    float* t1    = (float*)(ws + (size_t)N_CLS * FDIM * 2);
    float* cc    = t1 + N_CLS;
    float* accum = cc + N_CLS;

    zero_kernel<<<1, 1, 0, stream>>>(accum);
    prep_kernel<<<N_CLS, 256, 0, stream>>>(bnd, proto, wgt, pf8, wf8, t1, cc);
    gemm_reduce_kernel<<<256, 512, 0, stream>>>(pf8, wf8, t1, cc, accum);
    finalize_kernel<<<1, 1, 0, stream>>>(accum, (float*)d_out);
}